// Round 1
// baseline (942.606 us; speedup 1.0000x reference)
//
#include <hip/hip_runtime.h>
#include <hip/hip_bf16.h>

#define DEVINL __device__ __forceinline__

constexpr int NN   = 100000;
constexpr int NE   = 1600000;
constexpr int DIN  = 256;
constexpr int DH   = 128;
constexpr int DOUT = 64;
constexpr float BN_EPS = 1e-5f;
constexpr int SCAN_B = 256;
constexpr int NB1 = (NN + SCAN_B - 1) / SCAN_B; // 391

typedef __attribute__((ext_vector_type(8))) short short8;
typedef __attribute__((ext_vector_type(4))) float f32x4;

DEVINL ushort f2bf(float f) {
  uint u = __builtin_bit_cast(uint, f);
  u += 0x7FFFu + ((u >> 16) & 1u);
  return (ushort)(u >> 16);
}
DEVINL float bf2f(ushort u) {
  return __builtin_bit_cast(float, ((uint)u) << 16);
}

// ---------------- CSR build ----------------

__global__ void k_hist(const int* __restrict__ dst, int* __restrict__ counts) {
  int e = blockIdx.x * 256 + threadIdx.x;
  if (e < NE) atomicAdd(&counts[dst[e]], 1);
}

__global__ void k_scan1(const int* __restrict__ counts, int* __restrict__ offs,
                        int* __restrict__ bsum, int n) {
  __shared__ int s[SCAN_B];
  const int t = threadIdx.x;
  const int i = blockIdx.x * SCAN_B + t;
  int v = (i < n) ? counts[i] : 0;
  int x = v;
  s[t] = x; __syncthreads();
  for (int off = 1; off < SCAN_B; off <<= 1) {
    int y = (t >= off) ? s[t - off] : 0;
    __syncthreads();
    x += y; s[t] = x;
    __syncthreads();
  }
  if (i < n) offs[i] = x - v;          // exclusive within block
  if (t == SCAN_B - 1) bsum[blockIdx.x] = x;
}

__global__ void k_scan2(int* __restrict__ bsum, int nb) {
  __shared__ int s[512];
  const int t = threadIdx.x;
  int v = (t < nb) ? bsum[t] : 0;
  int x = v;
  s[t] = x; __syncthreads();
  for (int off = 1; off < 512; off <<= 1) {
    int y = (t >= off) ? s[t - off] : 0;
    __syncthreads();
    x += y; s[t] = x;
    __syncthreads();
  }
  if (t < nb) bsum[t] = x - v;         // exclusive, in place
}

__global__ void k_scan3(const int* __restrict__ counts, int* __restrict__ offs,
                        const int* __restrict__ bsum, float* __restrict__ dinv, int n) {
  const int i = blockIdx.x * SCAN_B + threadIdx.x;
  if (i < n) {
    offs[i] += bsum[blockIdx.x];
    dinv[i] = rsqrtf((float)counts[i] + 1.0f);  // +1 self loop
  }
  if (i == 0) offs[n] = NE;
}

__global__ void k_fill(const int* __restrict__ src, const int* __restrict__ dst,
                       const int* __restrict__ offs, int* __restrict__ cursor,
                       int* __restrict__ csr) {
  int e = blockIdx.x * 256 + threadIdx.x;
  if (e < NE) {
    int d = dst[e];
    int p = offs[d] + atomicAdd(&cursor[d], 1);
    csr[p] = src[e];
  }
}

// ---------------- weight pack (fragment layout) ----------------
// Wp[((ks*NF + nf)*64 + lane)*8 + j] = bf16( W[(ks*32 + (lane>>4)*8 + j)*Nw + nf*16 + (lane&15)] )
__global__ void k_pack(const float* __restrict__ W, ushort* __restrict__ Wp, int K, int Nw) {
  int t = blockIdx.x * 256 + threadIdx.x;
  int total = (K / 32) * (Nw / 16) * 64;
  if (t >= total) return;
  int l  = t & 63;
  int nf = (t >> 6) % (Nw / 16);
  int ks = (t >> 6) / (Nw / 16);
  int krow = ks * 32 + (l >> 4) * 8;
  int col  = nf * 16 + (l & 15);
  ushort out[8];
#pragma unroll
  for (int j = 0; j < 8; ++j) out[j] = f2bf(W[(size_t)(krow + j) * Nw + col]);
  *(uint4*)&Wp[(size_t)t * 8] = *(const uint4*)out;
}

// ---------------- GEMM: C[M,NW] = bnrelu(A[M,K]) @ W ----------------
template <int K, int NW, bool BN, bool F32OUT>
__launch_bounds__(256)
__global__ void k_gemm(const float* __restrict__ A, const ushort* __restrict__ Wp,
                       const float* __restrict__ scale, const float* __restrict__ shift,
                       void* __restrict__ Cout, int M) {
  constexpr int LDA = 40;  // 32 + 8 pad (bf16 elems) to spread LDS banks
  __shared__ ushort lds[128 * LDA];
  const int t = threadIdx.x;
  const int lane = t & 63;
  const int wid = t >> 6;
  const int m0 = blockIdx.x * 128;

  constexpr int WAVES_N = (NW == 128) ? 2 : 1;
  constexpr int MF  = (NW == 128) ? 4 : 2;  // 16-row frags per wave (64 / 32 rows)
  constexpr int NFW = 4;                    // 64 cols per wave
  constexpr int NFT = NW / 16;
  const int wr = wid / WAVES_N;
  const int wc = wid % WAVES_N;
  const int mbase = wr * (MF * 16);
  const int nfg0 = wc * NFW;

  f32x4 acc[MF][NFW] = {};

  const int cg = t & 7;    // 8 col-groups of 4 f32
  const int r0 = t >> 3;   // 0..31

  const int nkt = K / 32;
  for (int kt = 0; kt < nkt; ++kt) {
    const int k0 = kt * 32;
    float4 s4 = {1.f, 1.f, 1.f, 1.f}, h4 = {0.f, 0.f, 0.f, 0.f};
    if (BN) {
      s4 = *(const float4*)&scale[k0 + cg * 4];
      h4 = *(const float4*)&shift[k0 + cg * 4];
    }
    __syncthreads();
#pragma unroll
    for (int p = 0; p < 4; ++p) {
      const int row = p * 32 + r0;
      const int grow = m0 + row;
      float4 v = {0.f, 0.f, 0.f, 0.f};
      if (grow < M) v = *(const float4*)&A[(size_t)grow * K + k0 + cg * 4];
      if (BN) {
        v.x = fmaxf(v.x * s4.x + h4.x, 0.f);
        v.y = fmaxf(v.y * s4.y + h4.y, 0.f);
        v.z = fmaxf(v.z * s4.z + h4.z, 0.f);
        v.w = fmaxf(v.w * s4.w + h4.w, 0.f);
      }
      ushort4 w;
      w.x = f2bf(v.x); w.y = f2bf(v.y); w.z = f2bf(v.z); w.w = f2bf(v.w);
      *(ushort4*)&lds[row * LDA + cg * 4] = w;
    }
    __syncthreads();

    short8 bfrag[NFW];
#pragma unroll
    for (int nf = 0; nf < NFW; ++nf) {
      const size_t bidx = ((size_t)(kt * NFT + nfg0 + nf) * 64 + lane) * 8;
      bfrag[nf] = *(const short8*)&Wp[bidx];
    }
#pragma unroll
    for (int mf = 0; mf < MF; ++mf) {
      const short8 af =
          *(const short8*)&lds[(mbase + mf * 16 + (lane & 15)) * LDA + ((lane >> 4) * 8)];
#pragma unroll
      for (int nf = 0; nf < NFW; ++nf)
        acc[mf][nf] = __builtin_amdgcn_mfma_f32_16x16x32_bf16(af, bfrag[nf], acc[mf][nf], 0, 0, 0);
    }
  }

#pragma unroll
  for (int mf = 0; mf < MF; ++mf) {
#pragma unroll
    for (int nf = 0; nf < NFW; ++nf) {
#pragma unroll
      for (int r = 0; r < 4; ++r) {
        const int grow = m0 + mbase + mf * 16 + (lane >> 4) * 4 + r;
        if (grow < M) {
          const int gcol = (nfg0 + nf) * 16 + (lane & 15);
          if (F32OUT)
            ((float*)Cout)[(size_t)grow * NW + gcol] = acc[mf][nf][r];
          else
            ((ushort*)Cout)[(size_t)grow * NW + gcol] = f2bf(acc[mf][nf][r]);
        }
      }
    }
  }
}

// ---------------- pull-propagate ----------------
// H[d] = dinv[d]*( sum_{s->d} G[s]*dinv[s] + G[d]*dinv[d] ) + b
__launch_bounds__(256)
__global__ void k_prop128(const ushort* __restrict__ G, const int* __restrict__ offs,
                          const int* __restrict__ csr, const float* __restrict__ dinv,
                          const float* __restrict__ bias, float* __restrict__ H, int n) {
  const int wid = threadIdx.x >> 6;
  const int lane = threadIdx.x & 63;
  const int nid = blockIdx.x * 4 + wid;
  if (nid >= n) return;
  const int d0 = lane * 2;
  const float di = dinv[nid];
  const size_t base = (size_t)nid * 128;
  ushort2 gs = *(const ushort2*)&G[base + d0];
  float a0 = bf2f(gs.x) * di;
  float a1 = bf2f(gs.y) * di;
  const int e1 = offs[nid + 1];
  for (int e = offs[nid]; e < e1; ++e) {
    const int s = csr[e];
    const float ds = dinv[s];
    ushort2 g = *(const ushort2*)&G[(size_t)s * 128 + d0];
    a0 += bf2f(g.x) * ds;
    a1 += bf2f(g.y) * ds;
  }
  const float2 b2 = *(const float2*)&bias[d0];
  float2 o;
  o.x = a0 * di + b2.x;
  o.y = a1 * di + b2.y;
  *(float2*)&H[base + d0] = o;
}

__launch_bounds__(256)
__global__ void k_prop64(const float* __restrict__ G, const int* __restrict__ offs,
                         const int* __restrict__ csr, const float* __restrict__ dinv,
                         const float* __restrict__ bias, float* __restrict__ out, int n) {
  const int wid = threadIdx.x >> 6;
  const int lane = threadIdx.x & 63;
  const int nid = blockIdx.x * 4 + wid;
  if (nid >= n) return;
  const float di = dinv[nid];
  float a = G[(size_t)nid * 64 + lane] * di;
  const int e1 = offs[nid + 1];
  for (int e = offs[nid]; e < e1; ++e) {
    const int s = csr[e];
    a += G[(size_t)s * 64 + lane] * dinv[s];
  }
  out[(size_t)nid * 64 + lane] = a * di + bias[lane];
}

// ---------------- BN stats ----------------
__launch_bounds__(256)
__global__ void k_stats(const float* __restrict__ H, float* __restrict__ sum,
                        float* __restrict__ sumsq, int n) {
  const int d = threadIdx.x & 127;
  const int half = threadIdx.x >> 7;
  const int rpb = (n + gridDim.x - 1) / gridDim.x;
  const int r0 = blockIdx.x * rpb;
  const int r1 = min(n, r0 + rpb);
  float s = 0.f, q = 0.f;
  for (int r = r0 + half; r < r1; r += 2) {
    const float v = H[(size_t)r * 128 + d];
    s += v;
    q += v * v;
  }
  __shared__ float ls[256], lq[256];
  ls[threadIdx.x] = s;
  lq[threadIdx.x] = q;
  __syncthreads();
  if (half == 0) {
    atomicAdd(&sum[d], s + ls[d + 128]);
    atomicAdd(&sumsq[d], q + lq[d + 128]);
  }
}

__global__ void k_finalize(const float* __restrict__ sum, const float* __restrict__ sumsq,
                           const float* __restrict__ g, const float* __restrict__ bt,
                           float* __restrict__ scale, float* __restrict__ shift) {
  const int d = threadIdx.x;
  const float inv_n = 1.0f / (float)NN;
  const float mu = sum[d] * inv_n;
  float var = sumsq[d] * inv_n - mu * mu;
  const float rs = rsqrtf(var + BN_EPS);
  const float sc = g[d] * rs;
  scale[d] = sc;
  shift[d] = bt[d] - mu * sc;
}

// ---------------- launch ----------------
extern "C" void kernel_launch(void* const* d_in, const int* in_sizes, int n_in,
                              void* d_out, int out_size, void* d_ws, size_t ws_size,
                              hipStream_t stream) {
  const float* x   = (const float*)d_in[0];
  const int*  ei   = (const int*)d_in[1];
  const int*  srcp = ei;
  const int*  dstp = ei + NE;
  const float* W1  = (const float*)d_in[2];
  const float* b1  = (const float*)d_in[3];
  const float* g1  = (const float*)d_in[4];
  const float* bt1 = (const float*)d_in[5];
  const float* W2  = (const float*)d_in[6];
  const float* b2  = (const float*)d_in[7];
  const float* g2  = (const float*)d_in[8];
  const float* bt2 = (const float*)d_in[9];
  const float* W3  = (const float*)d_in[10];
  const float* b3  = (const float*)d_in[11];
  float* out = (float*)d_out;

  char* p = (char*)d_ws;
  auto alloc = [&](size_t bytes) {
    char* r = p;
    p += (bytes + 255) & ~(size_t)255;
    return r;
  };
  int*    counts = (int*)alloc(NN * 4);
  int*    offs   = (int*)alloc((NN + 1) * 4);
  int*    cursor = (int*)alloc(NN * 4);
  int*    bsum   = (int*)alloc(NB1 * 4);
  int*    csr    = (int*)alloc((size_t)NE * 4);
  float*  dinv   = (float*)alloc(NN * 4);
  float*  sum    = (float*)alloc(DH * 4);
  float*  sumsq  = (float*)alloc(DH * 4);
  float*  scale  = (float*)alloc(DH * 4);
  float*  shift  = (float*)alloc(DH * 4);
  ushort* Wp1    = (ushort*)alloc((size_t)DIN * DH * 2);
  ushort* Wp2    = (ushort*)alloc((size_t)DH * DH * 2);
  ushort* Wp3    = (ushort*)alloc((size_t)DH * DOUT * 2);
  ushort* G      = (ushort*)alloc((size_t)NN * DH * 2);   // bf16 GEMM out (layers 1,2)
  float*  G3     = (float*)G;                              // f32 GEMM out (layer 3): N*64*4 == N*128*2
  float*  H      = (float*)alloc((size_t)NN * DH * 4);

  const int EB = (NE + 255) / 256;      // 6250
  const int GB = (NN + 127) / 128;      // 782
  const int PB = (NN + 3) / 4;          // 25000

  // CSR build
  hipMemsetAsync(counts, 0, NN * 4, stream);
  hipMemsetAsync(cursor, 0, NN * 4, stream);
  k_hist<<<EB, 256, 0, stream>>>(dstp, counts);
  k_scan1<<<NB1, SCAN_B, 0, stream>>>(counts, offs, bsum, NN);
  k_scan2<<<1, 512, 0, stream>>>(bsum, NB1);
  k_scan3<<<NB1, SCAN_B, 0, stream>>>(counts, offs, bsum, dinv, NN);
  k_fill<<<EB, 256, 0, stream>>>(srcp, dstp, offs, cursor, csr);

  // weight packing
  k_pack<<<16, 256, 0, stream>>>(W1, Wp1, DIN, DH);
  k_pack<<<8, 256, 0, stream>>>(W2, Wp2, DH, DH);
  k_pack<<<4, 256, 0, stream>>>(W3, Wp3, DH, DOUT);

  // layer 1
  k_gemm<DIN, DH, false, false><<<GB, 256, 0, stream>>>(x, Wp1, nullptr, nullptr, G, NN);
  k_prop128<<<PB, 256, 0, stream>>>(G, offs, csr, dinv, b1, H, NN);
  hipMemsetAsync(sum, 0, DH * 4, stream);
  hipMemsetAsync(sumsq, 0, DH * 4, stream);
  k_stats<<<512, 256, 0, stream>>>(H, sum, sumsq, NN);
  k_finalize<<<1, DH, 0, stream>>>(sum, sumsq, g1, bt1, scale, shift);

  // layer 2
  k_gemm<DH, DH, true, false><<<GB, 256, 0, stream>>>(H, Wp2, scale, shift, G, NN);
  k_prop128<<<PB, 256, 0, stream>>>(G, offs, csr, dinv, b2, H, NN);
  hipMemsetAsync(sum, 0, DH * 4, stream);
  hipMemsetAsync(sumsq, 0, DH * 4, stream);
  k_stats<<<512, 256, 0, stream>>>(H, sum, sumsq, NN);
  k_finalize<<<1, DH, 0, stream>>>(sum, sumsq, g2, bt2, scale, shift);

  // layer 3 (f32 GEMM output, no BN after)
  k_gemm<DH, DOUT, true, true><<<GB, 256, 0, stream>>>(H, Wp3, scale, shift, (void*)G3, NN);
  k_prop64<<<PB, 256, 0, stream>>>(G3, offs, csr, dinv, b3, out, NN);
}

// Round 2
// 692.185 us; speedup vs baseline: 1.3618x; 1.3618x over previous
//
#include <hip/hip_runtime.h>
#include <hip/hip_bf16.h>

#define DEVINL __device__ __forceinline__

constexpr int NN   = 100000;
constexpr int NE   = 1600000;
constexpr int DIN  = 256;
constexpr int DH   = 128;
constexpr int DOUT = 64;
constexpr float BN_EPS = 1e-5f;
constexpr int SCAN_B = 256;
constexpr int NB1 = (NN + SCAN_B - 1) / SCAN_B; // 391

typedef __attribute__((ext_vector_type(8))) short short8;
typedef __attribute__((ext_vector_type(4))) float f32x4;

DEVINL ushort f2bf(float f) {
  uint u = __builtin_bit_cast(uint, f);
  u += 0x7FFFu + ((u >> 16) & 1u);
  return (ushort)(u >> 16);
}
DEVINL float bf2f(ushort u) {
  return __builtin_bit_cast(float, ((uint)u) << 16);
}

// ---------------- CSR build ----------------

__global__ void k_hist(const int* __restrict__ dst, int* __restrict__ counts) {
  int e = blockIdx.x * 256 + threadIdx.x;
  if (e < NE) atomicAdd(&counts[dst[e]], 1);
}

__global__ void k_scan1(const int* __restrict__ counts, int* __restrict__ offs,
                        int* __restrict__ bsum, int n) {
  __shared__ int s[SCAN_B];
  const int t = threadIdx.x;
  const int i = blockIdx.x * SCAN_B + t;
  int v = (i < n) ? counts[i] : 0;
  int x = v;
  s[t] = x; __syncthreads();
  for (int off = 1; off < SCAN_B; off <<= 1) {
    int y = (t >= off) ? s[t - off] : 0;
    __syncthreads();
    x += y; s[t] = x;
    __syncthreads();
  }
  if (i < n) offs[i] = x - v;          // exclusive within block
  if (t == SCAN_B - 1) bsum[blockIdx.x] = x;
}

__global__ void k_scan2(int* __restrict__ bsum, int nb) {
  __shared__ int s[512];
  const int t = threadIdx.x;
  int v = (t < nb) ? bsum[t] : 0;
  int x = v;
  s[t] = x; __syncthreads();
  for (int off = 1; off < 512; off <<= 1) {
    int y = (t >= off) ? s[t - off] : 0;
    __syncthreads();
    x += y; s[t] = x;
    __syncthreads();
  }
  if (t < nb) bsum[t] = x - v;         // exclusive, in place
}

__global__ void k_scan3(const int* __restrict__ counts, int* __restrict__ offs,
                        const int* __restrict__ bsum, float* __restrict__ dinv, int n) {
  const int i = blockIdx.x * SCAN_B + threadIdx.x;
  if (i < n) {
    offs[i] += bsum[blockIdx.x];
    dinv[i] = rsqrtf((float)counts[i] + 1.0f);  // +1 self loop
  }
  if (i == 0) offs[n] = NE;
}

__global__ void k_fill(const int* __restrict__ src, const int* __restrict__ dst,
                       const int* __restrict__ offs, int* __restrict__ cursor,
                       int* __restrict__ csr) {
  int e = blockIdx.x * 256 + threadIdx.x;
  if (e < NE) {
    int d = dst[e];
    int p = offs[d] + atomicAdd(&cursor[d], 1);
    csr[p] = src[e];
  }
}

// ---------------- weight pack (fragment layout) ----------------
// Wp[((ks*NF + nf)*64 + lane)*8 + j] = bf16( W[(ks*32 + (lane>>4)*8 + j)*Nw + nf*16 + (lane&15)] )
__global__ void k_pack(const float* __restrict__ W, ushort* __restrict__ Wp, int K, int Nw) {
  int t = blockIdx.x * 256 + threadIdx.x;
  int total = (K / 32) * (Nw / 16) * 64;
  if (t >= total) return;
  int l  = t & 63;
  int nf = (t >> 6) % (Nw / 16);
  int ks = (t >> 6) / (Nw / 16);
  int krow = ks * 32 + (l >> 4) * 8;
  int col  = nf * 16 + (l & 15);
  ushort out[8];
#pragma unroll
  for (int j = 0; j < 8; ++j) out[j] = f2bf(W[(size_t)(krow + j) * Nw + col]);
  *(uint4*)&Wp[(size_t)t * 8] = *(const uint4*)out;
}

// ---------------- GEMM: C[M,NW] = bf16( (bnrelu(A[M,K]) @ W) * dinv[row] ) ----------------
template <int K, int NW, bool BN>
__launch_bounds__(256)
__global__ void k_gemm(const float* __restrict__ A, const ushort* __restrict__ Wp,
                       const float* __restrict__ scale, const float* __restrict__ shift,
                       const float* __restrict__ dinv, ushort* __restrict__ Cout, int M) {
  constexpr int LDA = 40;  // 32 + 8 pad (bf16 elems) to spread LDS banks
  __shared__ ushort lds[128 * LDA];
  const int t = threadIdx.x;
  const int lane = t & 63;
  const int wid = t >> 6;
  const int m0 = blockIdx.x * 128;

  constexpr int WAVES_N = (NW == 128) ? 2 : 1;
  constexpr int MF  = (NW == 128) ? 4 : 2;  // 16-row frags per wave
  constexpr int NFW = 4;                    // 64 cols per wave
  constexpr int NFT = NW / 16;
  const int wr = wid / WAVES_N;
  const int wc = wid % WAVES_N;
  const int mbase = wr * (MF * 16);
  const int nfg0 = wc * NFW;

  f32x4 acc[MF][NFW] = {};

  const int cg = t & 7;    // 8 col-groups of 4 f32
  const int r0 = t >> 3;   // 0..31

  const int nkt = K / 32;
  for (int kt = 0; kt < nkt; ++kt) {
    const int k0 = kt * 32;
    float4 s4 = {1.f, 1.f, 1.f, 1.f}, h4 = {0.f, 0.f, 0.f, 0.f};
    if (BN) {
      s4 = *(const float4*)&scale[k0 + cg * 4];
      h4 = *(const float4*)&shift[k0 + cg * 4];
    }
    __syncthreads();
#pragma unroll
    for (int p = 0; p < 4; ++p) {
      const int row = p * 32 + r0;
      const int grow = m0 + row;
      float4 v = {0.f, 0.f, 0.f, 0.f};
      if (grow < M) v = *(const float4*)&A[(size_t)grow * K + k0 + cg * 4];
      if (BN) {
        v.x = fmaxf(v.x * s4.x + h4.x, 0.f);
        v.y = fmaxf(v.y * s4.y + h4.y, 0.f);
        v.z = fmaxf(v.z * s4.z + h4.z, 0.f);
        v.w = fmaxf(v.w * s4.w + h4.w, 0.f);
      }
      ushort4 w;
      w.x = f2bf(v.x); w.y = f2bf(v.y); w.z = f2bf(v.z); w.w = f2bf(v.w);
      *(ushort4*)&lds[row * LDA + cg * 4] = w;
    }
    __syncthreads();

    short8 bfrag[NFW];
#pragma unroll
    for (int nf = 0; nf < NFW; ++nf) {
      const size_t bidx = ((size_t)(kt * NFT + nfg0 + nf) * 64 + lane) * 8;
      bfrag[nf] = *(const short8*)&Wp[bidx];
    }
#pragma unroll
    for (int mf = 0; mf < MF; ++mf) {
      const short8 af =
          *(const short8*)&lds[(mbase + mf * 16 + (lane & 15)) * LDA + ((lane >> 4) * 8)];
#pragma unroll
      for (int nf = 0; nf < NFW; ++nf)
        acc[mf][nf] = __builtin_amdgcn_mfma_f32_16x16x32_bf16(af, bfrag[nf], acc[mf][nf], 0, 0, 0);
    }
  }

#pragma unroll
  for (int mf = 0; mf < MF; ++mf) {
#pragma unroll
    for (int r = 0; r < 4; ++r) {
      const int grow = m0 + mbase + mf * 16 + (lane >> 4) * 4 + r;
      if (grow < M) {
        const float dv = dinv[grow];   // pre-scale rows: G' = G * dinv
#pragma unroll
        for (int nf = 0; nf < NFW; ++nf) {
          const int gcol = (nfg0 + nf) * 16 + (lane & 15);
          Cout[(size_t)grow * NW + gcol] = f2bf(acc[mf][nf][r] * dv);
        }
      }
    }
  }
}

// ---------------- pull-propagate ----------------
// G' already scaled by dinv[src].  H[d] = dinv[d]*( sum_{s->d} G'[s] + G'[d] ) + b
__launch_bounds__(256)
__global__ void k_prop128(const ushort* __restrict__ G, const int* __restrict__ offs,
                          const int* __restrict__ csr, const float* __restrict__ dinv,
                          const float* __restrict__ bias, float* __restrict__ H, int n) {
  const int wid = threadIdx.x >> 6;
  const int lane = threadIdx.x & 63;
  const int nid = blockIdx.x * 4 + wid;
  if (nid >= n) return;
  const int d0 = lane * 2;
  const size_t base = (size_t)nid * 128;
  ushort2 gs = *(const ushort2*)&G[base + d0];
  float a0 = bf2f(gs.x);   // self term (already * dinv)
  float a1 = bf2f(gs.y);
  const int e0 = offs[nid];
  const int e1 = offs[nid + 1];
  for (int e = e0; e < e1; e += 8) {
    int idx[8];
#pragma unroll
    for (int i = 0; i < 8; ++i) idx[i] = (e + i < e1) ? csr[e + i] : nid;
    ushort2 g[8];
#pragma unroll
    for (int i = 0; i < 8; ++i) g[i] = *(const ushort2*)&G[(size_t)idx[i] * 128 + d0];
#pragma unroll
    for (int i = 0; i < 8; ++i) {
      if (e + i < e1) {   // wave-uniform predicate
        a0 += bf2f(g[i].x);
        a1 += bf2f(g[i].y);
      }
    }
  }
  const float di = dinv[nid];
  const float2 b2 = *(const float2*)&bias[d0];
  float2 o;
  o.x = a0 * di + b2.x;
  o.y = a1 * di + b2.y;
  *(float2*)&H[base + d0] = o;
}

__launch_bounds__(256)
__global__ void k_prop64(const ushort* __restrict__ G, const int* __restrict__ offs,
                         const int* __restrict__ csr, const float* __restrict__ dinv,
                         const float* __restrict__ bias, float* __restrict__ out, int n) {
  const int wid = threadIdx.x >> 6;
  const int lane = threadIdx.x & 63;
  const int nid = blockIdx.x * 4 + wid;
  if (nid >= n) return;
  float a = bf2f(G[(size_t)nid * 64 + lane]);   // self term
  const int e0 = offs[nid];
  const int e1 = offs[nid + 1];
  for (int e = e0; e < e1; e += 8) {
    int idx[8];
#pragma unroll
    for (int i = 0; i < 8; ++i) idx[i] = (e + i < e1) ? csr[e + i] : nid;
    ushort g[8];
#pragma unroll
    for (int i = 0; i < 8; ++i) g[i] = G[(size_t)idx[i] * 64 + lane];
#pragma unroll
    for (int i = 0; i < 8; ++i)
      if (e + i < e1) a += bf2f(g[i]);
  }
  out[(size_t)nid * 64 + lane] = a * dinv[nid] + bias[lane];
}

// ---------------- BN stats ----------------
__launch_bounds__(256)
__global__ void k_stats(const float* __restrict__ H, float* __restrict__ sum,
                        float* __restrict__ sumsq, int n) {
  const int d = threadIdx.x & 127;
  const int half = threadIdx.x >> 7;
  const int rpb = (n + gridDim.x - 1) / gridDim.x;
  const int r0 = blockIdx.x * rpb;
  const int r1 = min(n, r0 + rpb);
  float s = 0.f, q = 0.f;
  for (int r = r0 + half; r < r1; r += 2) {
    const float v = H[(size_t)r * 128 + d];
    s += v;
    q += v * v;
  }
  __shared__ float ls[256], lq[256];
  ls[threadIdx.x] = s;
  lq[threadIdx.x] = q;
  __syncthreads();
  if (half == 0) {
    atomicAdd(&sum[d], s + ls[d + 128]);
    atomicAdd(&sumsq[d], q + lq[d + 128]);
  }
}

__global__ void k_finalize(const float* __restrict__ sum, const float* __restrict__ sumsq,
                           const float* __restrict__ g, const float* __restrict__ bt,
                           float* __restrict__ scale, float* __restrict__ shift) {
  const int d = threadIdx.x;
  const float inv_n = 1.0f / (float)NN;
  const float mu = sum[d] * inv_n;
  float var = sumsq[d] * inv_n - mu * mu;
  const float rs = rsqrtf(var + BN_EPS);
  const float sc = g[d] * rs;
  scale[d] = sc;
  shift[d] = bt[d] - mu * sc;
}

// ---------------- launch ----------------
extern "C" void kernel_launch(void* const* d_in, const int* in_sizes, int n_in,
                              void* d_out, int out_size, void* d_ws, size_t ws_size,
                              hipStream_t stream) {
  const float* x   = (const float*)d_in[0];
  const int*  ei   = (const int*)d_in[1];
  const int*  srcp = ei;
  const int*  dstp = ei + NE;
  const float* W1  = (const float*)d_in[2];
  const float* b1  = (const float*)d_in[3];
  const float* g1  = (const float*)d_in[4];
  const float* bt1 = (const float*)d_in[5];
  const float* W2  = (const float*)d_in[6];
  const float* b2  = (const float*)d_in[7];
  const float* g2  = (const float*)d_in[8];
  const float* bt2 = (const float*)d_in[9];
  const float* W3  = (const float*)d_in[10];
  const float* b3  = (const float*)d_in[11];
  float* out = (float*)d_out;

  char* p = (char*)d_ws;
  auto alloc = [&](size_t bytes) {
    char* r = p;
    p += (bytes + 255) & ~(size_t)255;
    return r;
  };
  int*    counts = (int*)alloc(NN * 4);
  int*    offs   = (int*)alloc((NN + 1) * 4);
  int*    cursor = (int*)alloc(NN * 4);
  int*    bsum   = (int*)alloc(NB1 * 4);
  int*    csr    = (int*)alloc((size_t)NE * 4);
  float*  dinv   = (float*)alloc(NN * 4);
  float*  sum    = (float*)alloc(DH * 4);
  float*  sumsq  = (float*)alloc(DH * 4);
  float*  scale  = (float*)alloc(DH * 4);
  float*  shift  = (float*)alloc(DH * 4);
  ushort* Wp1    = (ushort*)alloc((size_t)DIN * DH * 2);
  ushort* Wp2    = (ushort*)alloc((size_t)DH * DH * 2);
  ushort* Wp3    = (ushort*)alloc((size_t)DH * DOUT * 2);
  ushort* G      = (ushort*)alloc((size_t)NN * DH * 2);   // bf16 pre-scaled GEMM out
  float*  H      = (float*)alloc((size_t)NN * DH * 4);

  const int EB = (NE + 255) / 256;      // 6250
  const int GB = (NN + 127) / 128;      // 782
  const int PB = (NN + 3) / 4;          // 25000

  // CSR build
  hipMemsetAsync(counts, 0, NN * 4, stream);
  hipMemsetAsync(cursor, 0, NN * 4, stream);
  k_hist<<<EB, 256, 0, stream>>>(dstp, counts);
  k_scan1<<<NB1, SCAN_B, 0, stream>>>(counts, offs, bsum, NN);
  k_scan2<<<1, 512, 0, stream>>>(bsum, NB1);
  k_scan3<<<NB1, SCAN_B, 0, stream>>>(counts, offs, bsum, dinv, NN);
  k_fill<<<EB, 256, 0, stream>>>(srcp, dstp, offs, cursor, csr);

  // weight packing
  k_pack<<<16, 256, 0, stream>>>(W1, Wp1, DIN, DH);
  k_pack<<<8, 256, 0, stream>>>(W2, Wp2, DH, DH);
  k_pack<<<4, 256, 0, stream>>>(W3, Wp3, DH, DOUT);

  // layer 1
  k_gemm<DIN, DH, false><<<GB, 256, 0, stream>>>(x, Wp1, nullptr, nullptr, dinv, G, NN);
  k_prop128<<<PB, 256, 0, stream>>>(G, offs, csr, dinv, b1, H, NN);
  hipMemsetAsync(sum, 0, DH * 4, stream);
  hipMemsetAsync(sumsq, 0, DH * 4, stream);
  k_stats<<<512, 256, 0, stream>>>(H, sum, sumsq, NN);
  k_finalize<<<1, DH, 0, stream>>>(sum, sumsq, g1, bt1, scale, shift);

  // layer 2
  k_gemm<DH, DH, true><<<GB, 256, 0, stream>>>(H, Wp2, scale, shift, dinv, G, NN);
  k_prop128<<<PB, 256, 0, stream>>>(G, offs, csr, dinv, b2, H, NN);
  hipMemsetAsync(sum, 0, DH * 4, stream);
  hipMemsetAsync(sumsq, 0, DH * 4, stream);
  k_stats<<<512, 256, 0, stream>>>(H, sum, sumsq, NN);
  k_finalize<<<1, DH, 0, stream>>>(sum, sumsq, g2, bt2, scale, shift);

  // layer 3 (bf16 pre-scaled output like the others)
  k_gemm<DH, DOUT, true><<<GB, 256, 0, stream>>>(H, Wp3, scale, shift, dinv, G, NN);
  k_prop64<<<PB, 256, 0, stream>>>(G, offs, csr, dinv, b3, out, NN);
}